// Round 3
// baseline (116.212 us; speedup 1.0000x reference)
//
#include <hip/hip_runtime.h>
#include <math.h>

// ChamferDistance: B=4, N=M=8192, 3-D fp32 points.
// out[0] = mean_i sqrt(min_j d2)*w  +  mean_j sqrt(min_i d2)
// d2 = ||q||^2 + (||r||^2 - 2 q.r); min over the parenthesized term only.
//
// R3 change: refs are wave-uniform -> read them via uniform (scalar) loads
// from a prepped float4 array instead of LDS. R2 was DS-pipe-bound (4x
// ds_read_b128 ~48 DS-cyc vs 28 CU-normalized VALU-cyc per iter -> 1.7x).
// Prepped layout per point: (-2x, -2y, -2z, ||p||^2) so the inner pair is
// exactly 3 FMA: d = fma(qx,rx, fma(qy,ry, fma(qz,rz, rsq))).

#define EPS 1e-8f

constexpr int B_    = 4;
constexpr int N_    = 8192;            // points per batch (N == M)
constexpr int TPB   = 256;
constexpr int QPT   = 8;               // queries per thread
constexpr int QT    = TPB * QPT;       // 2048 queries per block
constexpr int RCH   = 32;              // ref chunks (grid.y)
constexpr int CHUNK = N_ / RCH;        // 256 refs per block
constexpr int RB    = 64;              // reduce blocks
constexpr unsigned int INF_BITS = 0x7F7FFFFFu;   // FLT_MAX bits

// prep: pack both clouds, init min arrays, zero the output accumulator.
// one thread per point-index t in [0, B*N).
__global__ __launch_bounds__(TPB)
void prep_kernel(const float* __restrict__ src, const float* __restrict__ tgt,
                 float4* __restrict__ srcP, float4* __restrict__ tgtP,
                 unsigned int* __restrict__ minA, unsigned int* __restrict__ minB,
                 float* __restrict__ out)
{
    int t = blockIdx.x * TPB + threadIdx.x;
    {
        const float* p = src + (size_t)t * 3;
        float x = p[0], y = p[1], z = p[2];
        srcP[t] = make_float4(-2.f * x, -2.f * y, -2.f * z, x * x + y * y + z * z);
    }
    {
        const float* p = tgt + (size_t)t * 3;
        float x = p[0], y = p[1], z = p[2];
        tgtP[t] = make_float4(-2.f * x, -2.f * y, -2.f * z, x * x + y * y + z * z);
    }
    minA[t] = INF_BITS;
    minB[t] = INF_BITS;
    if (t == 0) out[0] = 0.f;
}

// grid: (N/QT=4, RCH=32, 2*B=8) = 1024 blocks -> 4 blocks/CU, 16 waves/CU.
__global__ __launch_bounds__(TPB)
void nn_min_kernel(const float4* __restrict__ srcP,
                   const float4* __restrict__ tgtP,
                   unsigned int* __restrict__ minA,
                   unsigned int* __restrict__ minB)
{
    const int zb  = blockIdx.z;
    const int dir = zb >> 2;            // 0: src queries tgt, 1: tgt queries src
    const int b   = zb & 3;
    const float4* q4 = (dir ? tgtP : srcP) + (size_t)b * N_;
    const float4* r4 = (dir ? srcP : tgtP) + (size_t)b * N_ + (size_t)blockIdx.y * CHUNK;
    unsigned int* omin = (dir ? minB : minA) + (size_t)b * N_;

    const int qbase = blockIdx.x * QT;
    const int tid   = threadIdx.x;

    // queries: prepped coords are (-2x,..); recover raw via *(-0.5)
    float qx[QPT], qy[QPT], qz[QPT], qs[QPT], mn[QPT];
#pragma unroll
    for (int qi = 0; qi < QPT; ++qi) {
        float4 q = q4[qbase + qi * TPB + tid];
        qx[qi] = -0.5f * q.x;
        qy[qi] = -0.5f * q.y;
        qz[qi] = -0.5f * q.z;
        qs[qi] = q.w;
        mn[qi] = 3.0e38f;
    }

    // inner loop: 8 uniform refs per iter (s_load), 3 FMA per pair
    for (int j = 0; j < CHUNK; j += 8) {
        float4 r[8];
#pragma unroll
        for (int u = 0; u < 8; ++u) r[u] = r4[j + u];
#pragma unroll
        for (int qi = 0; qi < QPT; ++qi) {
            float d[8];
#pragma unroll
            for (int u = 0; u < 8; ++u)
                d[u] = fmaf(qx[qi], r[u].x,
                        fmaf(qy[qi], r[u].y,
                         fmaf(qz[qi], r[u].z, r[u].w)));
            mn[qi] = fminf(fminf(fminf(d[0], d[1]), fminf(d[2], d[3])),
                           fminf(fminf(d[4], d[5]),
                                 fminf(fminf(d[6], d[7]), mn[qi])));
        }
    }

    // combine across ref chunks: atomicMin on uint bits (values >= 0)
#pragma unroll
    for (int qi = 0; qi < QPT; ++qi) {
        float d2 = fmaxf(mn[qi] + qs[qi], 0.0f);   // guard cancellation
        atomicMin(&omin[qbase + qi * TPB + tid], __float_as_uint(d2));
    }
}

// single reduce: partial sums -> wave/block reduce -> atomicAdd into out[0]
__global__ __launch_bounds__(TPB)
void reduce_kernel(const unsigned int* __restrict__ minA,
                   const unsigned int* __restrict__ minB,
                   const float* __restrict__ w,
                   float* __restrict__ out)
{
    const int BN = B_ * N_;
    const float invBN = 1.0f / (float)BN;

    float sum = 0.0f;
    for (int t = blockIdx.x * TPB + threadIdx.x; t < BN; t += RB * TPB) {
        sum += sqrtf(__uint_as_float(minA[t]) + EPS) * w[t];
        sum += sqrtf(__uint_as_float(minB[t]) + EPS);
    }
    sum *= invBN;

    __shared__ float ss[TPB / 64];
    int lane = threadIdx.x & 63;
    int wid  = threadIdx.x >> 6;
#pragma unroll
    for (int off = 32; off > 0; off >>= 1) sum += __shfl_down(sum, off);
    if (lane == 0) ss[wid] = sum;
    __syncthreads();
    if (threadIdx.x == 0) {
        float s = 0.0f;
#pragma unroll
        for (int i = 0; i < TPB / 64; ++i) s += ss[i];
        atomicAdd(out, s);
    }
}

extern "C" void kernel_launch(void* const* d_in, const int* in_sizes, int n_in,
                              void* d_out, int out_size, void* d_ws, size_t ws_size,
                              hipStream_t stream)
{
    const float* src = (const float*)d_in[0];   // (B, N, 3)
    const float* tgt = (const float*)d_in[1];   // (B, M, 3)
    const float* w   = (const float*)d_in[2];   // (B, N)
    float* out = (float*)d_out;

    const int BN = B_ * N_;
    float4* srcP = (float4*)d_ws;                       // BN float4
    float4* tgtP = srcP + BN;                           // BN float4
    unsigned int* minA = (unsigned int*)(tgtP + BN);    // BN uint
    unsigned int* minB = minA + BN;                     // BN uint

    prep_kernel<<<BN / TPB, TPB, 0, stream>>>(src, tgt, srcP, tgtP, minA, minB, out);

    dim3 grid(N_ / QT, RCH, 2 * B_);   // 4 x 32 x 8 = 1024 blocks
    nn_min_kernel<<<grid, TPB, 0, stream>>>(srcP, tgtP, minA, minB);

    reduce_kernel<<<RB, TPB, 0, stream>>>(minA, minB, w, out);
}

// Round 4
// 101.681 us; speedup vs baseline: 1.1429x; 1.1429x over previous
//
#include <hip/hip_runtime.h>
#include <math.h>

// ChamferDistance: B=4, N=M=8192, 3-D fp32 points.
// out[0] = mean_i sqrt(min_j d2)*w  +  mean_j sqrt(min_i d2)
// d2 = ||q||^2 + (||r||^2 - 2 q.r); min over the parenthesized term only.
//
// R4: packed-FP32 (v_pk_fma_f32) inner loop. Two QUERIES per float2 lane
// register (natural packing); refs broadcast from LDS (R2-style staging —
// R3's scalar-load experiment regressed). Per 2 refs x 2 queries:
// 6 pk_fma + 2 min3 -> 2.25 lane-inst/pair vs R2's 4.25, and QPT=16 drops
// DS-pipe demand to ~7 us (vs 27 at QPT=4), so the kernel is VALU-bound.
// Refs prepped as (-2x,-2y,-2z,||r||^2): inner pair = pure fma chain.

#define EPS 1e-8f

typedef float v2 __attribute__((ext_vector_type(2)));

constexpr int B_    = 4;
constexpr int N_    = 8192;            // points per batch (N == M)
constexpr int TPB   = 256;
constexpr int PAIRS = 8;               // query PAIRS per thread
constexpr int QPT   = 2 * PAIRS;       // 16 queries per thread
constexpr int QT    = TPB * QPT;       // 4096 queries per block
constexpr int RCH   = 64;              // ref chunks (grid.y)
constexpr int CHUNK = N_ / RCH;        // 128 refs staged per block
constexpr int RB    = 64;              // reduce blocks
constexpr unsigned int INF_BITS = 0x7F7FFFFFu;   // FLT_MAX bits

// prep: pack both clouds as (-2x,-2y,-2z,|p|^2), init mins, zero out[0].
__global__ __launch_bounds__(TPB)
void prep_kernel(const float* __restrict__ src, const float* __restrict__ tgt,
                 float4* __restrict__ srcP, float4* __restrict__ tgtP,
                 unsigned int* __restrict__ minA, unsigned int* __restrict__ minB,
                 float* __restrict__ out)
{
    int t = blockIdx.x * TPB + threadIdx.x;
    {
        const float* p = src + (size_t)t * 3;
        float x = p[0], y = p[1], z = p[2];
        srcP[t] = make_float4(-2.f * x, -2.f * y, -2.f * z, x * x + y * y + z * z);
    }
    {
        const float* p = tgt + (size_t)t * 3;
        float x = p[0], y = p[1], z = p[2];
        tgtP[t] = make_float4(-2.f * x, -2.f * y, -2.f * z, x * x + y * y + z * z);
    }
    minA[t] = INF_BITS;
    minB[t] = INF_BITS;
    if (t == 0) out[0] = 0.f;
}

// grid: (N/QT=2, RCH=64, 2*B=8) = 1024 blocks -> 4 blocks/CU, 16 waves/CU.
__global__ __launch_bounds__(TPB, 4)   // cap VGPR at 128 -> 4 waves/SIMD
void nn_min_kernel(const float4* __restrict__ srcP,
                   const float4* __restrict__ tgtP,
                   unsigned int* __restrict__ minA,
                   unsigned int* __restrict__ minB)
{
    __shared__ float4 sref[CHUNK];   // 2 KB: (-2x, -2y, -2z, |r|^2)

    const int zb  = blockIdx.z;
    const int dir = zb >> 2;            // 0: src queries tgt, 1: tgt queries src
    const int b   = zb & 3;
    const float4* q4 = (dir ? tgtP : srcP) + (size_t)b * N_;
    const float4* r4 = (dir ? srcP : tgtP) + (size_t)b * N_ + (size_t)blockIdx.y * CHUNK;
    unsigned int* omin = (dir ? minB : minA) + (size_t)b * N_;

    const int qbase = blockIdx.x * QT;
    const int tid   = threadIdx.x;

    if (tid < CHUNK) sref[tid] = r4[tid];

    // two queries packed per float2: lane-register {queryA, queryB}.
    // prepped coords are (-2x,..); recover raw via *(-0.5).
    v2 qx[PAIRS], qy[PAIRS], qz[PAIRS], qs[PAIRS], mn[PAIRS];
#pragma unroll
    for (int p = 0; p < PAIRS; ++p) {
        float4 qa = q4[qbase + (2 * p) * TPB + tid];
        float4 qb = q4[qbase + (2 * p + 1) * TPB + tid];
        qx[p] = v2{-0.5f * qa.x, -0.5f * qb.x};
        qy[p] = v2{-0.5f * qa.y, -0.5f * qb.y};
        qz[p] = v2{-0.5f * qa.z, -0.5f * qb.z};
        qs[p] = v2{qa.w, qb.w};
        mn[p] = v2{3.0e38f, 3.0e38f};
    }
    __syncthreads();

    // inner: 2 refs/iter; refs splat to both packed halves (loop-hoisted movs),
    // 3 v_pk_fma_f32 per ref per query-pair, min3 folding per 2 refs.
    for (int j = 0; j < CHUNK; j += 2) {
        float4 a = sref[j];
        float4 b2 = sref[j + 1];
        v2 ax = v2{a.x, a.x},  ay = v2{a.y, a.y},  az = v2{a.z, a.z},  aw = v2{a.w, a.w};
        v2 bx = v2{b2.x, b2.x}, by = v2{b2.y, b2.y}, bz = v2{b2.z, b2.z}, bw = v2{b2.w, b2.w};
#pragma unroll
        for (int p = 0; p < PAIRS; ++p) {
            v2 d0 = ax * qx[p] + (ay * qy[p] + (az * qz[p] + aw));   // 3 pk_fma
            v2 d1 = bx * qx[p] + (by * qy[p] + (bz * qz[p] + bw));   // 3 pk_fma
            mn[p].x = fminf(fminf(d0.x, d1.x), mn[p].x);             // v_min3
            mn[p].y = fminf(fminf(d0.y, d1.y), mn[p].y);             // v_min3
        }
    }

    // combine across ref chunks: atomicMin on uint bits (values >= 0)
#pragma unroll
    for (int p = 0; p < PAIRS; ++p) {
        int i0 = qbase + (2 * p) * TPB + tid;
        int i1 = i0 + TPB;
        float d0 = fmaxf(mn[p].x + qs[p].x, 0.0f);
        float d1 = fmaxf(mn[p].y + qs[p].y, 0.0f);
        atomicMin(&omin[i0], __float_as_uint(d0));
        atomicMin(&omin[i1], __float_as_uint(d1));
    }
}

// single reduce: partial sums -> wave/block reduce -> atomicAdd into out[0]
__global__ __launch_bounds__(TPB)
void reduce_kernel(const unsigned int* __restrict__ minA,
                   const unsigned int* __restrict__ minB,
                   const float* __restrict__ w,
                   float* __restrict__ out)
{
    const int BN = B_ * N_;
    const float invBN = 1.0f / (float)BN;

    float sum = 0.0f;
    for (int t = blockIdx.x * TPB + threadIdx.x; t < BN; t += RB * TPB) {
        sum += sqrtf(__uint_as_float(minA[t]) + EPS) * w[t];
        sum += sqrtf(__uint_as_float(minB[t]) + EPS);
    }
    sum *= invBN;

    __shared__ float ss[TPB / 64];
    int lane = threadIdx.x & 63;
    int wid  = threadIdx.x >> 6;
#pragma unroll
    for (int off = 32; off > 0; off >>= 1) sum += __shfl_down(sum, off);
    if (lane == 0) ss[wid] = sum;
    __syncthreads();
    if (threadIdx.x == 0) {
        float s = 0.0f;
#pragma unroll
        for (int i = 0; i < TPB / 64; ++i) s += ss[i];
        atomicAdd(out, s);
    }
}

extern "C" void kernel_launch(void* const* d_in, const int* in_sizes, int n_in,
                              void* d_out, int out_size, void* d_ws, size_t ws_size,
                              hipStream_t stream)
{
    const float* src = (const float*)d_in[0];   // (B, N, 3)
    const float* tgt = (const float*)d_in[1];   // (B, M, 3)
    const float* w   = (const float*)d_in[2];   // (B, N)
    float* out = (float*)d_out;

    const int BN = B_ * N_;
    float4* srcP = (float4*)d_ws;                       // BN float4
    float4* tgtP = srcP + BN;                           // BN float4
    unsigned int* minA = (unsigned int*)(tgtP + BN);    // BN uint
    unsigned int* minB = minA + BN;                     // BN uint

    prep_kernel<<<BN / TPB, TPB, 0, stream>>>(src, tgt, srcP, tgtP, minA, minB, out);

    dim3 grid(N_ / QT, RCH, 2 * B_);   // 2 x 64 x 8 = 1024 blocks
    nn_min_kernel<<<grid, TPB, 0, stream>>>(srcP, tgtP, minA, minB);

    reduce_kernel<<<RB, TPB, 0, stream>>>(minA, minB, w, out);
}